// Round 1
// baseline (548.073 us; speedup 1.0000x reference)
//
#include <hip/hip_runtime.h>
#include <math.h>

#define BATCH 2048
#define SEQ   512

struct Lut16 { float v[16]; };

// ---------------- Phase 1: quantum_conv as a 16-entry LUT ----------------
// patch bits (p_k > 127) -> basis state; fixed RY/CNOT layers; mean p(|1>).
__global__ void conv_kernel(const float* __restrict__ x, float* __restrict__ conv, Lut16 lut) {
    __shared__ float slut[16];
    if (threadIdx.x < 16) slut[threadIdx.x] = lut.v[threadIdx.x];
    __syncthreads();
    int p = blockIdx.x * blockDim.x + threadIdx.x;
    const int total = BATCH * SEQ;
    if (p < total) {
        float4 v = reinterpret_cast<const float4*>(x)[p];
        int idx = ((v.x > 127.0f) ? 8 : 0) | ((v.y > 127.0f) ? 4 : 0) |
                  ((v.z > 127.0f) ? 2 : 0) | ((v.w > 127.0f) ? 1 : 0);
        conv[p] = slut[idx];
    }
}

// ---------------- Phase 2: LSTM with closed-form qlayer ----------------
__device__ __forceinline__ float sigmoid_f(float z) {
    return 1.0f / (1.0f + __expf(-z));
}
__device__ __forceinline__ float tanh_f(float z) {
    // |z| <= ~2.1 here, so exp(2z) <= ~70: no overflow risk.
    float e = __expf(2.0f * z);
    return (e - 1.0f) / (e + 1.0f);
}

__global__ __launch_bounds__(64) void lstm_kernel(
    const float* __restrict__ conv,
    const float* __restrict__ Wf, const float* __restrict__ bf, const float* __restrict__ rxf,
    const float* __restrict__ Wi, const float* __restrict__ bi, const float* __restrict__ rxi,
    const float* __restrict__ Wu, const float* __restrict__ bu, const float* __restrict__ rxu,
    const float* __restrict__ Wo, const float* __restrict__ bo, const float* __restrict__ rxo,
    const float* __restrict__ Wout, const float* __restrict__ bout,
    float* __restrict__ out)
{
    int bidx = blockIdx.x * blockDim.x + threadIdx.x; // batch element
    if (bidx >= BATCH) return;

    // Hoist all weights into registers (wave-uniform addresses -> broadcast loads).
    const float* Ws[4] = {Wf, Wi, Wu, Wo};
    const float* bs[4] = {bf, bi, bu, bo};
    const float* rs[4] = {rxf, rxi, rxu, rxo};
    float W[4][4][5];   // [gate][wire][comb]
    float B2[4][4];     // b + rx folded (RX(z)RX(rx) == RX(z+rx))
#pragma unroll
    for (int g = 0; g < 4; ++g) {
#pragma unroll
        for (int w = 0; w < 4; ++w) {
#pragma unroll
            for (int j = 0; j < 5; ++j) W[g][w][j] = Ws[g][w * 5 + j];
            B2[g][w] = bs[g][w] + rs[g][w];
        }
    }
    float wo[4];
#pragma unroll
    for (int w = 0; w < 4; ++w) wo[w] = Wout[w];
    const float bo_out = bout[0];

    float h[4] = {0.f, 0.f, 0.f, 0.f};
    float c[4] = {0.f, 0.f, 0.f, 0.f};

    const float* convRow = conv + (size_t)bidx * SEQ;
    float* outCol = out + bidx;

    for (int t = 0; t < SEQ; ++t) {
        float xt = convRow[t];
        float gate[4][4]; // [gate][wire] = <Z_w> pre-activation
#pragma unroll
        for (int g = 0; g < 4; ++g) {
            float ct[4];
#pragma unroll
            for (int w = 0; w < 4; ++w) {
                float z = B2[g][w] + W[g][w][0] * xt;
#pragma unroll
                for (int j = 0; j < 4; ++j) z += W[g][w][j + 1] * h[j];
                ct[w] = __cosf(z);
            }
            // Z0=c1c2c3, Z1=c0c1, Z2=c0c1c2, Z3=c0c1c2c3
            float u  = ct[2] * ct[3];
            float z1 = ct[0] * ct[1];
            gate[g][0] = ct[1] * u;
            gate[g][1] = z1;
            gate[g][2] = z1 * ct[2];
            gate[g][3] = z1 * u;
        }
#pragma unroll
        for (int w = 0; w < 4; ++w) {
            float f  = sigmoid_f(gate[0][w]);
            float i_ = sigmoid_f(gate[1][w]);
            float g_ = tanh_f(gate[2][w]);
            float o  = sigmoid_f(gate[3][w]);
            c[w] = f * c[w] + i_ * g_;
            h[w] = o * tanh_f(c[w]);
        }
        float y = bo_out;
#pragma unroll
        for (int w = 0; w < 4; ++w) y += h[w] * wo[w];
        outCol[(size_t)t * BATCH] = y;
    }
}

// ---------------- Host: LUT for the fixed random circuit ----------------
static void compute_lut(float out[16]) {
    // np.random.RandomState(0).uniform(0, 2pi, (2,4)) -- canonical seed-0 MT19937 doubles
    static const double u[8] = {
        0.5488135039273248, 0.7151893663724195, 0.6027633760716439, 0.5448831829968969,
        0.4236547993389047, 0.6458941130666561, 0.4375872112626925, 0.8917730007820798
    };
    double ang[8];
    for (int k = 0; k < 8; ++k)
        ang[k] = (double)(float)(u[k] * 2.0 * 3.14159265358979323846); // match .astype(float32)

    for (int p = 0; p < 16; ++p) {
        double a[16] = {0.0};
        a[p] = 1.0; // basis state (global phase of RX(pi) encoding irrelevant)
        for (int layer = 0; layer < 2; ++layer) {
            for (int w = 0; w < 4; ++w) {
                double th = ang[layer * 4 + w] * 0.5;
                double cth = cos(th), sth = sin(th);
                int bit = 1 << (3 - w);
                for (int i = 0; i < 16; ++i) if (!(i & bit)) {
                    double a0 = a[i], a1 = a[i | bit];
                    a[i]       = cth * a0 - sth * a1;
                    a[i | bit] = sth * a0 + cth * a1;
                }
            }
            for (int w = 0; w < 3; ++w) { // CNOT(w, w+1)
                int cb = 1 << (3 - w), tb = 1 << (3 - (w + 1));
                for (int i = 0; i < 16; ++i) if ((i & cb) && !(i & tb)) {
                    double tmp = a[i]; a[i] = a[i | tb]; a[i | tb] = tmp;
                }
            }
        }
        double s = 0.0;
        for (int w = 0; w < 4; ++w) {
            int bit = 1 << (3 - w);
            for (int i = 0; i < 16; ++i) if (i & bit) s += a[i] * a[i];
        }
        out[p] = (float)(s * 0.25);
    }
}

extern "C" void kernel_launch(void* const* d_in, const int* in_sizes, int n_in,
                              void* d_out, int out_size, void* d_ws, size_t ws_size,
                              hipStream_t stream) {
    const float* x = (const float*)d_in[0];
    const float *Wf, *bf, *rxf, *Wi, *bi, *rxi, *Wu, *bu, *rxu, *Wo, *bo, *rxo, *Wout, *bout;
    if (in_sizes[3] == 20) {
        // reference-signature order: x, W_f,b_f, W_i,b_i, W_u,b_u, W_o,b_o, rx_f,rx_i,rx_u,rx_o, W_out,b_out
        Wf  = (const float*)d_in[1];  bf  = (const float*)d_in[2];
        Wi  = (const float*)d_in[3];  bi  = (const float*)d_in[4];
        Wu  = (const float*)d_in[5];  bu  = (const float*)d_in[6];
        Wo  = (const float*)d_in[7];  bo  = (const float*)d_in[8];
        rxf = (const float*)d_in[9];  rxi = (const float*)d_in[10];
        rxu = (const float*)d_in[11]; rxo = (const float*)d_in[12];
    } else {
        // setup_inputs() dict order: x, (W,b,rx) per gate f,i,u,o, W_out, b_out
        Wf  = (const float*)d_in[1];  bf  = (const float*)d_in[2];  rxf = (const float*)d_in[3];
        Wi  = (const float*)d_in[4];  bi  = (const float*)d_in[5];  rxi = (const float*)d_in[6];
        Wu  = (const float*)d_in[7];  bu  = (const float*)d_in[8];  rxu = (const float*)d_in[9];
        Wo  = (const float*)d_in[10]; bo  = (const float*)d_in[11]; rxo = (const float*)d_in[12];
    }
    Wout = (const float*)d_in[13];
    bout = (const float*)d_in[14];

    float* conv = (float*)d_ws; // BATCH*SEQ floats = 4 MB
    Lut16 lut;
    compute_lut(lut.v);

    const int total = BATCH * SEQ;
    conv_kernel<<<(total + 255) / 256, 256, 0, stream>>>(x, conv, lut);
    lstm_kernel<<<BATCH / 64, 64, 0, stream>>>(conv,
        Wf, bf, rxf, Wi, bi, rxi, Wu, bu, rxu, Wo, bo, rxo,
        Wout, bout, (float*)d_out);
}

// Round 2
// 153.774 us; speedup vs baseline: 3.5641x; 3.5641x over previous
//
#include <hip/hip_runtime.h>
#include <math.h>

#define BATCH 2048
#define SEQ   512

struct Lut16 { float v[16]; };

// ---------------- Phase 1: quantum_conv as a 16-entry LUT ----------------
__global__ void conv_kernel(const float* __restrict__ x, float* __restrict__ conv, Lut16 lut) {
    __shared__ float slut[16];
    if (threadIdx.x < 16) slut[threadIdx.x] = lut.v[threadIdx.x];
    __syncthreads();
    int p = blockIdx.x * blockDim.x + threadIdx.x;
    const int total = BATCH * SEQ;
    if (p < total) {
        float4 v = reinterpret_cast<const float4*>(x)[p];
        int idx = ((v.x > 127.0f) ? 8 : 0) | ((v.y > 127.0f) ? 4 : 0) |
                  ((v.z > 127.0f) ? 2 : 0) | ((v.w > 127.0f) ? 1 : 0);
        conv[p] = slut[idx];
    }
}

// ---------------- quad_perm DPP helpers (xor within quad) ----------------
template <int CTRL>
__device__ __forceinline__ float dppx(float x) {
    return __int_as_float(__builtin_amdgcn_mov_dpp(__float_as_int(x), CTRL, 0xF, 0xF, true));
}
#define DPP_XOR1 0xB1  // quad_perm [1,0,3,2]
#define DPP_XOR2 0x4E  // quad_perm [2,3,0,1]
#define DPP_XOR3 0x1B  // quad_perm [3,2,1,0]

__device__ __forceinline__ float rcp_f(float x) { return __builtin_amdgcn_rcpf(x); }
__device__ __forceinline__ float sigm(float x) { return rcp_f(1.0f + __expf(-x)); }
__device__ __forceinline__ float tanh_f(float x) {
    float e = __expf(2.0f * x);           // args bounded (|x|<=~4): no overflow
    return (e - 1.0f) * rcp_f(e + 1.0f);
}

// ---------------- Phase 2: LSTM, 4 lanes per batch element ----------------
// lane w owns wire w; computes all 4 gates for that wire. All cross-lane
// traffic is quad_perm DPP (xor1/2/3 within the element's quad).
__global__ __launch_bounds__(64) void lstm_kernel(
    const float* __restrict__ conv,
    const float* __restrict__ Wf, const float* __restrict__ bf, const float* __restrict__ rxf,
    const float* __restrict__ Wi, const float* __restrict__ bi, const float* __restrict__ rxi,
    const float* __restrict__ Wu, const float* __restrict__ bu, const float* __restrict__ rxu,
    const float* __restrict__ Wo, const float* __restrict__ bo, const float* __restrict__ rxo,
    const float* __restrict__ Wout, const float* __restrict__ bout,
    float* __restrict__ out)
{
    const int tid  = blockIdx.x * 64 + threadIdx.x;  // grid covers exactly BATCH*4
    const int elem = tid >> 2;
    const int w    = tid & 3;

    const float* Ws[4] = {Wf, Wi, Wu, Wo};
    const float* bs[4] = {bf, bi, bu, bo};
    const float* rs[4] = {rxf, rxi, rxu, rxo};

    // Init-time weight permutation: Wp[g][m] multiplies y_m = h[w^m].
    float Wp[4][4], W0[4], B2[4];
#pragma unroll
    for (int g = 0; g < 4; ++g) {
        W0[g] = Ws[g][w * 5 + 0];
        B2[g] = bs[g][w] + rs[g][w];     // RX(z)RX(rx) == RX(z+rx): fold rx into bias
#pragma unroll
        for (int m = 0; m < 4; ++m) Wp[g][m] = Ws[g][w * 5 + 1 + (w ^ m)];
    }
    // Pattern membership: Z0=c1c2c3, Z1=c0c1, Z2=c0c1c2, Z3=c0c1c2c3.
    // inc[m] = ((w^m) in S_w), loop-invariant per lane.
    bool inc[4];
#pragma unroll
    for (int m = 0; m < 4; ++m) {
        int j = w ^ m;
        inc[m] = (w == 0) ? (j != 0) : (j <= w);
    }
    const float wo_w  = Wout[w];
    const float bout0 = bout[0];

    float h = 0.0f, c = 0.0f;

    const float4* convRow4 = reinterpret_cast<const float4*>(conv + (size_t)elem * SEQ);
    float* outBase = out + elem;

    auto step = [&](float xt, int t) {
        // gather h[0..3] as y_m = h[w^m] (3 independent quad DPPs)
        float h1 = dppx<DPP_XOR1>(h);
        float h2 = dppx<DPP_XOR2>(h);
        float h3 = dppx<DPP_XOR3>(h);
        float ct[4];
#pragma unroll
        for (int g = 0; g < 4; ++g) {
            float za = __builtin_fmaf(W0[g], xt, B2[g]);
            float zb = __builtin_fmaf(Wp[g][1], h1, Wp[g][0] * h);
            float zc = __builtin_fmaf(Wp[g][3], h3, Wp[g][2] * h2);
            ct[g] = __cosf(za + zb + zc);
        }
        float gate[4];
#pragma unroll
        for (int g = 0; g < 4; ++g) {
            float x1 = dppx<DPP_XOR1>(ct[g]);
            float x2 = dppx<DPP_XOR2>(ct[g]);
            float x3 = dppx<DPP_XOR3>(ct[g]);
            float f0 = inc[0] ? ct[g] : 1.0f;
            float f1 = inc[1] ? x1 : 1.0f;
            float f2 = inc[2] ? x2 : 1.0f;
            float f3 = inc[3] ? x3 : 1.0f;
            gate[g] = (f0 * f1) * (f2 * f3);
        }
        float fg = sigm(gate[0]);
        float ig = sigm(gate[1]);
        float ug = tanh_f(gate[2]);
        float og = sigm(gate[3]);
        c = __builtin_fmaf(fg, c, ig * ug);
        h = og * tanh_f(c);
        // y = bout + sum_w h[w]*wo[w]: quad butterfly sum
        float p = h * wo_w;
        p += dppx<DPP_XOR1>(p);
        p += dppx<DPP_XOR2>(p);
        if (w == 0) outBase[(size_t)t * BATCH] = p + bout0;
    };

    float4 xb = convRow4[0];
    for (int tb = 0; tb < SEQ / 4; ++tb) {
        float4 xc = xb;
        int nb = (tb + 1 < SEQ / 4) ? (tb + 1) : (SEQ / 4 - 1);
        xb = convRow4[nb];                 // prefetch next 4 steps (latency hidden)
        int t0 = tb * 4;
        step(xc.x, t0 + 0);
        step(xc.y, t0 + 1);
        step(xc.z, t0 + 2);
        step(xc.w, t0 + 3);
    }
}

// ---------------- Host: LUT for the fixed random circuit ----------------
static void compute_lut(float out[16]) {
    static const double u[8] = {
        0.5488135039273248, 0.7151893663724195, 0.6027633760716439, 0.5448831829968969,
        0.4236547993389047, 0.6458941130666561, 0.4375872112626925, 0.8917730007820798
    };
    double ang[8];
    for (int k = 0; k < 8; ++k)
        ang[k] = (double)(float)(u[k] * 2.0 * 3.14159265358979323846);

    for (int p = 0; p < 16; ++p) {
        double a[16] = {0.0};
        a[p] = 1.0;
        for (int layer = 0; layer < 2; ++layer) {
            for (int w = 0; w < 4; ++w) {
                double th = ang[layer * 4 + w] * 0.5;
                double cth = cos(th), sth = sin(th);
                int bit = 1 << (3 - w);
                for (int i = 0; i < 16; ++i) if (!(i & bit)) {
                    double a0 = a[i], a1 = a[i | bit];
                    a[i]       = cth * a0 - sth * a1;
                    a[i | bit] = sth * a0 + cth * a1;
                }
            }
            for (int w = 0; w < 3; ++w) {
                int cb = 1 << (3 - w), tb = 1 << (3 - (w + 1));
                for (int i = 0; i < 16; ++i) if ((i & cb) && !(i & tb)) {
                    double tmp = a[i]; a[i] = a[i | tb]; a[i | tb] = tmp;
                }
            }
        }
        double s = 0.0;
        for (int w = 0; w < 4; ++w) {
            int bit = 1 << (3 - w);
            for (int i = 0; i < 16; ++i) if (i & bit) s += a[i] * a[i];
        }
        out[p] = (float)(s * 0.25);
    }
}

extern "C" void kernel_launch(void* const* d_in, const int* in_sizes, int n_in,
                              void* d_out, int out_size, void* d_ws, size_t ws_size,
                              hipStream_t stream) {
    const float* x = (const float*)d_in[0];
    const float *Wf, *bf, *rxf, *Wi, *bi, *rxi, *Wu, *bu, *rxu, *Wo, *bo, *rxo, *Wout, *bout;
    if (in_sizes[3] == 20) {
        Wf  = (const float*)d_in[1];  bf  = (const float*)d_in[2];
        Wi  = (const float*)d_in[3];  bi  = (const float*)d_in[4];
        Wu  = (const float*)d_in[5];  bu  = (const float*)d_in[6];
        Wo  = (const float*)d_in[7];  bo  = (const float*)d_in[8];
        rxf = (const float*)d_in[9];  rxi = (const float*)d_in[10];
        rxu = (const float*)d_in[11]; rxo = (const float*)d_in[12];
    } else {
        Wf  = (const float*)d_in[1];  bf  = (const float*)d_in[2];  rxf = (const float*)d_in[3];
        Wi  = (const float*)d_in[4];  bi  = (const float*)d_in[5];  rxi = (const float*)d_in[6];
        Wu  = (const float*)d_in[7];  bu  = (const float*)d_in[8];  rxu = (const float*)d_in[9];
        Wo  = (const float*)d_in[10]; bo  = (const float*)d_in[11]; rxo = (const float*)d_in[12];
    }
    Wout = (const float*)d_in[13];
    bout = (const float*)d_in[14];

    float* conv = (float*)d_ws; // BATCH*SEQ floats = 4 MB
    Lut16 lut;
    compute_lut(lut.v);

    const int total = BATCH * SEQ;
    conv_kernel<<<(total + 255) / 256, 256, 0, stream>>>(x, conv, lut);
    lstm_kernel<<<(BATCH * 4) / 64, 64, 0, stream>>>(conv,
        Wf, bf, rxf, Wi, bi, rxi, Wu, bu, rxu, Wo, bo, rxo,
        Wout, bout, (float*)d_out);
}

// Round 3
// 70.458 us; speedup vs baseline: 7.7787x; 2.1825x over previous
//
#include <hip/hip_runtime.h>
#include <math.h>

#define BATCH 2048
#define SEQ   512
#define CHUNKS   16
#define CHUNK_L  32      // SEQ / CHUNKS
#define WARMUP   96      // steps of warm-up before each chunk (contraction kills h0,c0 error)

struct Lut16 { float v[16]; };

// ---------------- Phase 1: quantum_conv as a 16-entry LUT ----------------
__global__ void conv_kernel(const float* __restrict__ x, float* __restrict__ conv, Lut16 lut) {
    __shared__ float slut[16];
    if (threadIdx.x < 16) slut[threadIdx.x] = lut.v[threadIdx.x];
    __syncthreads();
    int p = blockIdx.x * blockDim.x + threadIdx.x;
    const int total = BATCH * SEQ;
    if (p < total) {
        float4 v = reinterpret_cast<const float4*>(x)[p];
        int idx = ((v.x > 127.0f) ? 8 : 0) | ((v.y > 127.0f) ? 4 : 0) |
                  ((v.z > 127.0f) ? 2 : 0) | ((v.w > 127.0f) ? 1 : 0);
        conv[p] = slut[idx];
    }
}

// ---------------- quad_perm DPP helpers (xor within quad) ----------------
template <int CTRL>
__device__ __forceinline__ float dppx(float x) {
    return __int_as_float(__builtin_amdgcn_mov_dpp(__float_as_int(x), CTRL, 0xF, 0xF, true));
}
#define DPP_XOR1 0xB1  // quad_perm [1,0,3,2]
#define DPP_XOR2 0x4E  // quad_perm [2,3,0,1]
#define DPP_XOR3 0x1B  // quad_perm [3,2,1,0]

__device__ __forceinline__ float rcp_f(float x) { return __builtin_amdgcn_rcpf(x); }
__device__ __forceinline__ float sigm(float x) { return rcp_f(1.0f + __expf(-x)); }
__device__ __forceinline__ float tanh_f(float x) {
    float e = __expf(2.0f * x);           // args bounded (|x|<=~4): no overflow
    return (e - 1.0f) * rcp_f(e + 1.0f);
}

// ---------------- Phase 2: chunked LSTM, 4 lanes per batch element ----------------
// quad q = (chunk, elem); lane w owns wire w, computes all 4 gates for that wire.
// Chunk k emits t in [32k, 32k+32), warm-started at max(0, 32k-96) from h=c=0.
// Chunks 0..3 are exact; k>=4 rely on contraction (f in [0.27,0.73] since |Z|<=1).
__global__ __launch_bounds__(256) void lstm_kernel(
    const float* __restrict__ conv,
    const float* __restrict__ Wf, const float* __restrict__ bf, const float* __restrict__ rxf,
    const float* __restrict__ Wi, const float* __restrict__ bi, const float* __restrict__ rxi,
    const float* __restrict__ Wu, const float* __restrict__ bu, const float* __restrict__ rxu,
    const float* __restrict__ Wo, const float* __restrict__ bo, const float* __restrict__ rxo,
    const float* __restrict__ Wout, const float* __restrict__ bout,
    float* __restrict__ out)
{
    const int tid   = blockIdx.x * 256 + threadIdx.x;
    const int q     = tid >> 2;
    const int w     = tid & 3;
    const int chunk = q >> 11;          // 2048 quads (elements) per chunk -> wave-uniform
    const int elem  = q & 2047;
    const int c0    = chunk * CHUNK_L;
    const int s0    = (c0 > WARMUP) ? (c0 - WARMUP) : 0;

    const float* Ws[4] = {Wf, Wi, Wu, Wo};
    const float* bs[4] = {bf, bi, bu, bo};
    const float* rs[4] = {rxf, rxi, rxu, rxo};

    // Init-time weight permutation: Wp[g][m] multiplies h[w^m].
    float Wp[4][4], W0[4], B2[4];
#pragma unroll
    for (int g = 0; g < 4; ++g) {
        W0[g] = Ws[g][w * 5 + 0];
        B2[g] = bs[g][w] + rs[g][w];     // RX(z)RX(rx) == RX(z+rx): fold rx into bias
#pragma unroll
        for (int m = 0; m < 4; ++m) Wp[g][m] = Ws[g][w * 5 + 1 + (w ^ m)];
    }
    // Z0=c1c2c3, Z1=c0c1, Z2=c0c1c2, Z3=c0c1c2c3; inc[m] = ((w^m) in S_w)
    bool inc[4];
#pragma unroll
    for (int m = 0; m < 4; ++m) {
        int j = w ^ m;
        inc[m] = (w == 0) ? (j != 0) : (j <= w);
    }
    const float wo_w  = Wout[w];
    const float bout0 = bout[0];

    float h = 0.0f, c = 0.0f, ysave = 0.0f;

    const float4* row4 = reinterpret_cast<const float4*>(conv + (size_t)elem * SEQ);
    float4 xb = row4[s0 >> 2];

    for (int t0 = s0; t0 < c0 + CHUNK_L; t0 += 4) {
        float4 xc = xb;
        int nb = (t0 + 4 < c0 + CHUNK_L) ? ((t0 + 4) >> 2) : (t0 >> 2);
        xb = row4[nb];                               // prefetch next 4 steps
        const float xs[4] = {xc.x, xc.y, xc.z, xc.w};

        // za depends only on x_t: compute off the h-chain
        float za[4][4];
#pragma unroll
        for (int s = 0; s < 4; ++s)
#pragma unroll
            for (int g = 0; g < 4; ++g)
                za[s][g] = __builtin_fmaf(W0[g], xs[s], B2[g]);

#pragma unroll
        for (int s = 0; s < 4; ++s) {
            float h1 = dppx<DPP_XOR1>(h);
            float h2 = dppx<DPP_XOR2>(h);
            float h3 = dppx<DPP_XOR3>(h);
            float ct[4];
#pragma unroll
            for (int g = 0; g < 4; ++g) {
                float zb = __builtin_fmaf(Wp[g][1], h1, Wp[g][0] * h);
                float zc = __builtin_fmaf(Wp[g][3], h3, Wp[g][2] * h2);
                ct[g] = __cosf((za[s][g] + zb) + zc);
            }
            float gate[4];
#pragma unroll
            for (int g = 0; g < 4; ++g) {
                float x1 = dppx<DPP_XOR1>(ct[g]);
                float x2 = dppx<DPP_XOR2>(ct[g]);
                float x3 = dppx<DPP_XOR3>(ct[g]);
                float f0 = inc[0] ? ct[g] : 1.0f;
                float f1 = inc[1] ? x1 : 1.0f;
                float f2 = inc[2] ? x2 : 1.0f;
                float f3 = inc[3] ? x3 : 1.0f;
                gate[g] = (f0 * f1) * (f2 * f3);
            }
            float fg = sigm(gate[0]);
            float ig = sigm(gate[1]);
            float ug = tanh_f(gate[2]);
            float og = sigm(gate[3]);
            c = __builtin_fmaf(fg, c, ig * ug);
            h = og * tanh_f(c);
            // y = bout + sum_w h[w]*wo[w]: quad butterfly -> all lanes hold y
            float p = h * wo_w;
            p += dppx<DPP_XOR1>(p);
            p += dppx<DPP_XOR2>(p);
            float y = p + bout0;
            ysave = (w == s) ? y : ysave;            // lane w stashes sub-step w's y
        }
        if (t0 >= c0)                                 // wave-uniform branch
            out[(size_t)(t0 + w) * BATCH + elem] = ysave;  // 1 unmasked store / 4 steps
    }
}

// ---------------- Host: LUT for the fixed random circuit ----------------
static void compute_lut(float out[16]) {
    static const double u[8] = {
        0.5488135039273248, 0.7151893663724195, 0.6027633760716439, 0.5448831829968969,
        0.4236547993389047, 0.6458941130666561, 0.4375872112626925, 0.8917730007820798
    };
    double ang[8];
    for (int k = 0; k < 8; ++k)
        ang[k] = (double)(float)(u[k] * 2.0 * 3.14159265358979323846);

    for (int p = 0; p < 16; ++p) {
        double a[16] = {0.0};
        a[p] = 1.0;
        for (int layer = 0; layer < 2; ++layer) {
            for (int w = 0; w < 4; ++w) {
                double th = ang[layer * 4 + w] * 0.5;
                double cth = cos(th), sth = sin(th);
                int bit = 1 << (3 - w);
                for (int i = 0; i < 16; ++i) if (!(i & bit)) {
                    double a0 = a[i], a1 = a[i | bit];
                    a[i]       = cth * a0 - sth * a1;
                    a[i | bit] = sth * a0 + cth * a1;
                }
            }
            for (int w = 0; w < 3; ++w) {
                int cb = 1 << (3 - w), tb = 1 << (3 - (w + 1));
                for (int i = 0; i < 16; ++i) if ((i & cb) && !(i & tb)) {
                    double tmp = a[i]; a[i] = a[i | tb]; a[i | tb] = tmp;
                }
            }
        }
        double s = 0.0;
        for (int w = 0; w < 4; ++w) {
            int bit = 1 << (3 - w);
            for (int i = 0; i < 16; ++i) if (i & bit) s += a[i] * a[i];
        }
        out[p] = (float)(s * 0.25);
    }
}

extern "C" void kernel_launch(void* const* d_in, const int* in_sizes, int n_in,
                              void* d_out, int out_size, void* d_ws, size_t ws_size,
                              hipStream_t stream) {
    const float* x = (const float*)d_in[0];
    const float *Wf, *bf, *rxf, *Wi, *bi, *rxi, *Wu, *bu, *rxu, *Wo, *bo, *rxo, *Wout, *bout;
    if (in_sizes[3] == 20) {
        Wf  = (const float*)d_in[1];  bf  = (const float*)d_in[2];
        Wi  = (const float*)d_in[3];  bi  = (const float*)d_in[4];
        Wu  = (const float*)d_in[5];  bu  = (const float*)d_in[6];
        Wo  = (const float*)d_in[7];  bo  = (const float*)d_in[8];
        rxf = (const float*)d_in[9];  rxi = (const float*)d_in[10];
        rxu = (const float*)d_in[11]; rxo = (const float*)d_in[12];
    } else {
        Wf  = (const float*)d_in[1];  bf  = (const float*)d_in[2];  rxf = (const float*)d_in[3];
        Wi  = (const float*)d_in[4];  bi  = (const float*)d_in[5];  rxi = (const float*)d_in[6];
        Wu  = (const float*)d_in[7];  bu  = (const float*)d_in[8];  rxu = (const float*)d_in[9];
        Wo  = (const float*)d_in[10]; bo  = (const float*)d_in[11]; rxo = (const float*)d_in[12];
    }
    Wout = (const float*)d_in[13];
    bout = (const float*)d_in[14];

    float* conv = (float*)d_ws; // BATCH*SEQ floats = 4 MB
    Lut16 lut;
    compute_lut(lut.v);

    const int total = BATCH * SEQ;
    conv_kernel<<<(total + 255) / 256, 256, 0, stream>>>(x, conv, lut);
    const int lstm_threads = BATCH * CHUNKS * 4;   // 131072
    lstm_kernel<<<lstm_threads / 256, 256, 0, stream>>>(conv,
        Wf, bf, rxf, Wi, bi, rxi, Wu, bu, rxu, Wo, bo, rxo,
        Wout, bout, (float*)d_out);
}

// Round 4
// 39.028 us; speedup vs baseline: 14.0431x; 1.8053x over previous
//
#include <hip/hip_runtime.h>
#include <math.h>

#define BATCH 2048
#define SEQ   512
#define CHUNKS   16
#define CHUNK_L  32      // SEQ / CHUNKS
#define WARMUP   48      // contraction: f<=0.731 => 0.74^48*2.7 ~ 1e-6 carry-in error

typedef float v2f __attribute__((ext_vector_type(2)));

struct Lut16 { float v[16]; };

// ---------------- Phase 1: quantum_conv as a 16-entry LUT ----------------
__global__ void conv_kernel(const float* __restrict__ x, float* __restrict__ conv, Lut16 lut) {
    __shared__ float slut[16];
    if (threadIdx.x < 16) slut[threadIdx.x] = lut.v[threadIdx.x];
    __syncthreads();
    int p = blockIdx.x * blockDim.x + threadIdx.x;
    const int total = BATCH * SEQ;
    if (p < total) {
        float4 v = reinterpret_cast<const float4*>(x)[p];
        int idx = ((v.x > 127.0f) ? 8 : 0) | ((v.y > 127.0f) ? 4 : 0) |
                  ((v.z > 127.0f) ? 2 : 0) | ((v.w > 127.0f) ? 1 : 0);
        conv[p] = slut[idx];
    }
}

// ---------------- quad_perm DPP helpers (xor within quad) ----------------
template <int CTRL>
__device__ __forceinline__ float dppx(float x) {
    return __int_as_float(__builtin_amdgcn_mov_dpp(__float_as_int(x), CTRL, 0xF, 0xF, true));
}
#define DPP_XOR1 0xB1  // quad_perm [1,0,3,2]
#define DPP_XOR2 0x4E  // quad_perm [2,3,0,1]
#define DPP_XOR3 0x1B  // quad_perm [3,2,1,0]

template <int CTRL>
__device__ __forceinline__ v2f dpp2(v2f v) {
    v2f r; r.x = dppx<CTRL>(v.x); r.y = dppx<CTRL>(v.y); return r;
}
__device__ __forceinline__ v2f splat(float a) { v2f r; r.x = a; r.y = a; return r; }
__device__ __forceinline__ float rcp_f(float x) { return __builtin_amdgcn_rcpf(x); }

// sigma(x) = 0.5 + 0.5*tanh(x/2), tanh Taylor-9 (|x|<=1 => |y|<=0.5, err<1e-6)
#define SP0  0.5f
#define SP1 -0.16666667f
#define SP2  0.06666667f
#define SP3 -0.02698413f
#define SP4  0.01093474f

// ---------------- Phase 2: chunked LSTM, 4 lanes per batch element ----------------
__global__ __launch_bounds__(256) void lstm_kernel(
    const float* __restrict__ conv,
    const float* __restrict__ Wf, const float* __restrict__ bf, const float* __restrict__ rxf,
    const float* __restrict__ Wi, const float* __restrict__ bi, const float* __restrict__ rxi,
    const float* __restrict__ Wu, const float* __restrict__ bu, const float* __restrict__ rxu,
    const float* __restrict__ Wo, const float* __restrict__ bo, const float* __restrict__ rxo,
    const float* __restrict__ Wout, const float* __restrict__ bout,
    float* __restrict__ out)
{
    const int tid   = blockIdx.x * 256 + threadIdx.x;
    const int q     = tid >> 2;
    const int w     = tid & 3;
    const int chunk = q >> 11;          // 2048 elements per chunk -> wave-uniform
    const int elem  = q & 2047;
    const int c0    = chunk * CHUNK_L;
    const int s0    = (c0 > WARMUP) ? (c0 - WARMUP) : 0;

    const float* Ws[4] = {Wf, Wi, Wu, Wo};
    const float* bs[4] = {bf, bi, bu, bo};
    const float* rs[4] = {rxf, rxi, rxu, rxo};

    // Packed weights: pair01 = gates {f,i}, pair23 = gates {u,o}.
    // Wh..[m] multiplies h[w^m] (init-time permutation).
    v2f Wh01[4], Wh23[4], W0_01, W0_23, B2_01, B2_23;
#pragma unroll
    for (int m = 0; m < 4; ++m) {
        int col = 1 + (w ^ m);
        Wh01[m].x = Ws[0][w * 5 + col]; Wh01[m].y = Ws[1][w * 5 + col];
        Wh23[m].x = Ws[2][w * 5 + col]; Wh23[m].y = Ws[3][w * 5 + col];
    }
    W0_01.x = Ws[0][w * 5]; W0_01.y = Ws[1][w * 5];
    W0_23.x = Ws[2][w * 5]; W0_23.y = Ws[3][w * 5];
    B2_01.x = bs[0][w] + rs[0][w]; B2_01.y = bs[1][w] + rs[1][w];  // RX(z)RX(rx)==RX(z+rx)
    B2_23.x = bs[2][w] + rs[2][w]; B2_23.y = bs[3][w] + rs[3][w];

    const bool w_is0 = (w == 0), w_is1 = (w == 1), w_odd = (w & 1);
    const float wo_w  = Wout[w];
    const float bout0 = bout[0];
    const v2f one2 = splat(1.0f);

    float h = 0.0f, c = 0.0f, ysave = 0.0f;

    const float4* row4 = reinterpret_cast<const float4*>(conv + (size_t)elem * SEQ);
    float4 xb = row4[s0 >> 2];

    // One timestep. za01/za23 = B2 + W0*x_t (precomputed off-chain).
    auto step = [&](v2f za01, v2f za23, int s, bool emit) {
        float h1 = dppx<DPP_XOR1>(h);
        float h2 = dppx<DPP_XOR2>(h);
        float h3 = dppx<DPP_XOR3>(h);
        v2f hv = splat(h), h1v = splat(h1), h2v = splat(h2), h3v = splat(h3);

        // z = za + sum_m Wh[m]*h[w^m]  (serial pk-FMA chain, 4 per pair)
        v2f z01 = za01 + Wh01[0] * hv;  z01 = z01 + Wh01[1] * h1v;
        z01 = z01 + Wh01[2] * h2v;      z01 = z01 + Wh01[3] * h3v;
        v2f z23 = za23 + Wh23[0] * hv;  z23 = z23 + Wh23[1] * h1v;
        z23 = z23 + Wh23[2] * h2v;      z23 = z23 + Wh23[3] * h3v;

        // cos via hw v_cos (input in revolutions)
        v2f r01 = z01 * 0.15915494f, r23 = z23 * 0.15915494f;
        v2f ct01, ct23;
        ct01.x = __builtin_amdgcn_cosf(r01.x); ct01.y = __builtin_amdgcn_cosf(r01.y);
        ct23.x = __builtin_amdgcn_cosf(r23.x); ct23.y = __builtin_amdgcn_cosf(r23.y);

        // gate pre-activations: lane w needs prod over S_w of c_j (c_j in lane j)
        // pair products: m1 = c_w*c_{w^1} (=P01 in lanes 0,1; P23 in lanes 2,3); m2 = other pair's
        v2f x1_01 = dpp2<DPP_XOR1>(ct01), x1_23 = dpp2<DPP_XOR1>(ct23);
        v2f m1_01 = ct01 * x1_01,         m1_23 = ct23 * x1_23;
        v2f m2_01 = dpp2<DPP_XOR2>(m1_01), m2_23 = dpp2<DPP_XOR2>(m1_23);
        // lane0: x1*m2, lane1: m1, lane2: ct*m2, lane3: m1*m2
        v2f a01 = w_odd ? m1_01 : (w_is0 ? x1_01 : ct01);
        v2f a23 = w_odd ? m1_23 : (w_is0 ? x1_23 : ct23);
        v2f b01 = w_is1 ? one2 : m2_01;
        v2f b23 = w_is1 ? one2 : m2_23;
        v2f Z01 = a01 * b01;   // {Zf, Zi}
        v2f Z23 = a23 * b23;   // {Zu, Zo}

        // f,i = sigma(Z01): packed poly, no trans
        v2f y2 = Z01 * 0.5f, t2 = y2 * y2;
        v2f p2 = splat(SP3) + t2 * SP4;
        p2 = splat(SP2) + t2 * p2;
        p2 = splat(SP1) + t2 * p2;
        p2 = splat(SP0) + t2 * p2;
        v2f sig = splat(0.5f) + y2 * p2;

        // o = sigma(Z23.y): scalar poly
        float yo = 0.5f * Z23.y, to = yo * yo;
        float po = SP3 + to * SP4; po = SP2 + to * po; po = SP1 + to * po; po = SP0 + to * po;
        float og = 0.5f + yo * po;

        // u = tanh(Z23.x): Pade CF4 (err 5e-6 on [-1,1]), 1 rcp
        float xu = Z23.x, tu = xu * xu;
        float nu = 105.0f + tu * 10.0f;
        float du = 105.0f + tu * (45.0f + tu);
        float ug = (xu * nu) * rcp_f(du);

        c = sig.x * c + sig.y * ug;

        // tanh(c): Pade CF6 (err <1e-6 on |c|<=2.1), 1 rcp
        float tc = c * c;
        float nc = 1260.0f + tc * 21.0f; nc = 10395.0f + tc * nc;
        float dc = 210.0f + tc; dc = 4725.0f + tc * dc; dc = 10395.0f + tc * dc;
        h = og * ((c * nc) * rcp_f(dc));

        if (emit) {
            float p = h * wo_w;
            p += dppx<DPP_XOR1>(p);
            p += dppx<DPP_XOR2>(p);
            float y = p + bout0;
            ysave = (w == s) ? y : ysave;
        }
    };

    auto block4 = [&](int t0, bool emit) {
        float4 xc = xb;
        int nb = (t0 >> 2) + 1; nb = (nb < SEQ / 4) ? nb : (SEQ / 4 - 1);
        xb = row4[nb];                               // prefetch next 4 steps
        v2f za01[4], za23[4];
        const float xs[4] = {xc.x, xc.y, xc.z, xc.w};
#pragma unroll
        for (int s = 0; s < 4; ++s) {
            za01[s] = B2_01 + W0_01 * xs[s];
            za23[s] = B2_23 + W0_23 * xs[s];
        }
#pragma unroll
        for (int s = 0; s < 4; ++s) step(za01[s], za23[s], s, emit);
    };

    for (int t0 = s0; t0 < c0; t0 += 4) block4(t0, false);       // warm-up (no y)
    for (int t0 = c0; t0 < c0 + CHUNK_L; t0 += 4) {              // emit
        block4(t0, true);
        out[(size_t)(t0 + w) * BATCH + elem] = ysave;            // 1 store / 4 steps
    }
}

// ---------------- Host: LUT for the fixed random circuit ----------------
static void compute_lut(float out[16]) {
    static const double u[8] = {
        0.5488135039273248, 0.7151893663724195, 0.6027633760716439, 0.5448831829968969,
        0.4236547993389047, 0.6458941130666561, 0.4375872112626925, 0.8917730007820798
    };
    double ang[8];
    for (int k = 0; k < 8; ++k)
        ang[k] = (double)(float)(u[k] * 2.0 * 3.14159265358979323846);

    for (int p = 0; p < 16; ++p) {
        double a[16] = {0.0};
        a[p] = 1.0;
        for (int layer = 0; layer < 2; ++layer) {
            for (int w = 0; w < 4; ++w) {
                double th = ang[layer * 4 + w] * 0.5;
                double cth = cos(th), sth = sin(th);
                int bit = 1 << (3 - w);
                for (int i = 0; i < 16; ++i) if (!(i & bit)) {
                    double a0 = a[i], a1 = a[i | bit];
                    a[i]       = cth * a0 - sth * a1;
                    a[i | bit] = sth * a0 + cth * a1;
                }
            }
            for (int w = 0; w < 3; ++w) {
                int cb = 1 << (3 - w), tb = 1 << (3 - (w + 1));
                for (int i = 0; i < 16; ++i) if ((i & cb) && !(i & tb)) {
                    double tmp = a[i]; a[i] = a[i | tb]; a[i | tb] = tmp;
                }
            }
        }
        double s = 0.0;
        for (int w = 0; w < 4; ++w) {
            int bit = 1 << (3 - w);
            for (int i = 0; i < 16; ++i) if (i & bit) s += a[i] * a[i];
        }
        out[p] = (float)(s * 0.25);
    }
}

extern "C" void kernel_launch(void* const* d_in, const int* in_sizes, int n_in,
                              void* d_out, int out_size, void* d_ws, size_t ws_size,
                              hipStream_t stream) {
    const float* x = (const float*)d_in[0];
    const float *Wf, *bf, *rxf, *Wi, *bi, *rxi, *Wu, *bu, *rxu, *Wo, *bo, *rxo, *Wout, *bout;
    if (in_sizes[3] == 20) {
        Wf  = (const float*)d_in[1];  bf  = (const float*)d_in[2];
        Wi  = (const float*)d_in[3];  bi  = (const float*)d_in[4];
        Wu  = (const float*)d_in[5];  bu  = (const float*)d_in[6];
        Wo  = (const float*)d_in[7];  bo  = (const float*)d_in[8];
        rxf = (const float*)d_in[9];  rxi = (const float*)d_in[10];
        rxu = (const float*)d_in[11]; rxo = (const float*)d_in[12];
    } else {
        Wf  = (const float*)d_in[1];  bf  = (const float*)d_in[2];  rxf = (const float*)d_in[3];
        Wi  = (const float*)d_in[4];  bi  = (const float*)d_in[5];  rxi = (const float*)d_in[6];
        Wu  = (const float*)d_in[7];  bu  = (const float*)d_in[8];  rxu = (const float*)d_in[9];
        Wo  = (const float*)d_in[10]; bo  = (const float*)d_in[11]; rxo = (const float*)d_in[12];
    }
    Wout = (const float*)d_in[13];
    bout = (const float*)d_in[14];

    float* conv = (float*)d_ws; // BATCH*SEQ floats = 4 MB
    Lut16 lut;
    compute_lut(lut.v);

    const int total = BATCH * SEQ;
    conv_kernel<<<(total + 255) / 256, 256, 0, stream>>>(x, conv, lut);
    const int lstm_threads = BATCH * CHUNKS * 4;   // 131072
    lstm_kernel<<<lstm_threads / 256, 256, 0, stream>>>(conv,
        Wf, bf, rxf, Wi, bi, rxi, Wu, bu, rxu, Wo, bo, rxo,
        Wout, bout, (float*)d_out);
}

// Round 5
// 36.874 us; speedup vs baseline: 14.8634x; 1.0584x over previous
//
#include <hip/hip_runtime.h>
#include <math.h>

#define BATCH 2048
#define SEQ   512
#define CHUNKS   16
#define CHUNK_L  32      // SEQ / CHUNKS
#define WARMUP   48      // contraction: f<=0.731 => carry-in error ~1e-6 at 48 steps

typedef float v2f __attribute__((ext_vector_type(2)));

struct Lut16 { float v[16]; };

// ---------------- packed fp32 (VOP3P) via inline asm ----------------
// hipcc does not reliably lower float2 ext_vector math to v_pk_*_f32; force it.
__device__ __forceinline__ v2f pk_fma(v2f a, v2f b, v2f c) {
    v2f d; asm("v_pk_fma_f32 %0, %1, %2, %3" : "=v"(d) : "v"(a), "v"(b), "v"(c)); return d;
}
__device__ __forceinline__ v2f pk_mul(v2f a, v2f b) {
    v2f d; asm("v_pk_mul_f32 %0, %1, %2" : "=v"(d) : "v"(a), "v"(b)); return d;
}

// ---------------- quad_perm DPP helpers ----------------
template <int CTRL>
__device__ __forceinline__ float dppx(float x) {
    return __int_as_float(__builtin_amdgcn_mov_dpp(__float_as_int(x), CTRL, 0xF, 0xF, true));
}
template <int CTRL>
__device__ __forceinline__ v2f dpp2(v2f v) {
    v2f r; r.x = dppx<CTRL>(v.x); r.y = dppx<CTRL>(v.y); return r;
}
#define DPP_XOR1 0xB1  // quad_perm [1,0,3,2]
#define DPP_XOR2 0x4E  // quad_perm [2,3,0,1]
#define DPP_XOR3 0x1B  // quad_perm [3,2,1,0]
#define DPP_BC0  0x00  // broadcast quad lane 0
#define DPP_BC1  0x55
#define DPP_BC2  0xAA
#define DPP_BC3  0xFF

__device__ __forceinline__ float rcp_f(float x) { return __builtin_amdgcn_rcpf(x); }

// sigma(x) = 0.5 + 0.5*tanh(x/2), tanh Taylor-9 (|arg|<=0.5, err<1e-6)
#define SP1 -0.16666667f
#define SP2  0.06666667f
#define SP3 -0.02698413f
#define SP4  0.01093474f

// ---------------- fused conv+LSTM: 4 lanes per batch element ----------------
// quad = (chunk, elem); lane w owns wire w, computes all 4 gates for that wire.
// conv is computed inline: 16B patch load -> threshold bits -> LDS LUT -> DPP
// broadcast; the whole za stage runs one 4-step block ahead (ping-pong A/B).
__global__ __launch_bounds__(256) void lstm_fused_kernel(
    const float* __restrict__ x,
    const float* __restrict__ Wf, const float* __restrict__ bf, const float* __restrict__ rxf,
    const float* __restrict__ Wi, const float* __restrict__ bi, const float* __restrict__ rxi,
    const float* __restrict__ Wu, const float* __restrict__ bu, const float* __restrict__ rxu,
    const float* __restrict__ Wo, const float* __restrict__ bo, const float* __restrict__ rxo,
    const float* __restrict__ Wout, const float* __restrict__ bout,
    Lut16 lut, float* __restrict__ out)
{
    __shared__ float slut[16];
    if (threadIdx.x < 16) slut[threadIdx.x] = lut.v[threadIdx.x];
    __syncthreads();

    const int tid   = blockIdx.x * 256 + threadIdx.x;
    const int q     = tid >> 2;
    const int w     = tid & 3;
    const int chunk = q >> 11;          // 2048 elements per chunk -> wave-uniform
    const int elem  = q & 2047;
    const int c0    = chunk * CHUNK_L;
    const int s0    = (c0 > WARMUP) ? (c0 - WARMUP) : 0;
    const int tend  = c0 + CHUNK_L;

    const float* Ws[4] = {Wf, Wi, Wu, Wo};
    const float* bs[4] = {bf, bi, bu, bo};
    const float* rs[4] = {rxf, rxi, rxu, rxo};

    // Packed weights: pair01 = gates {f,i}, pair23 = gates {u,o}.
    v2f Wh01[4], Wh23[4], W0_01, W0_23, B2_01, B2_23;
#pragma unroll
    for (int m = 0; m < 4; ++m) {
        int col = 1 + (w ^ m);
        Wh01[m].x = Ws[0][w * 5 + col]; Wh01[m].y = Ws[1][w * 5 + col];
        Wh23[m].x = Ws[2][w * 5 + col]; Wh23[m].y = Ws[3][w * 5 + col];
    }
    W0_01.x = Ws[0][w * 5]; W0_01.y = Ws[1][w * 5];
    W0_23.x = Ws[2][w * 5]; W0_23.y = Ws[3][w * 5];
    B2_01.x = bs[0][w] + rs[0][w]; B2_01.y = bs[1][w] + rs[1][w];  // RX(z)RX(rx)==RX(z+rx)
    B2_23.x = bs[2][w] + rs[2][w]; B2_23.y = bs[3][w] + rs[3][w];

    const bool w_is0 = (w == 0), w_is1 = (w == 1), w_odd = (w & 1);
    const float wo_w  = Wout[w];
    const float bout0 = bout[0];

    // loop-invariant packed constants (hoisted into VGPR pairs)
    const v2f one2  = {1.0f, 1.0f};
    const v2f half2 = {0.5f, 0.5f};
    const v2f itp2  = {0.15915494f, 0.15915494f};   // 1/(2*pi)
    const v2f sp1   = {SP1, SP1}, sp2 = {SP2, SP2}, sp3 = {SP3, SP3}, sp4 = {SP4, SP4};

    float h = 0.0f, c = 0.0f, ysave = 0.0f;
    v2f hd = {0.0f, 0.0f};              // duplicated h (feeds packed FMAs, no splats)

    const float4* x4 = reinterpret_cast<const float4*>(x);
    const size_t rowb = (size_t)elem * SEQ + w;
    auto ldx = [&](int t) {
        int tc = (t < tend - 4) ? t : (tend - 4);
        return x4[rowb + tc];
    };

    // za stage: patch -> bits -> LUT -> quad-broadcast -> za = B2 + W0*x (all off-chain)
    auto make_za = [&](float4 vx, v2f* za01, v2f* za23) {
        int idx = ((vx.x > 127.0f) ? 8 : 0) | ((vx.y > 127.0f) ? 4 : 0) |
                  ((vx.z > 127.0f) ? 2 : 0) | ((vx.w > 127.0f) ? 1 : 0);
        float xq = slut[idx];
        v2f xqd; xqd.x = xq; xqd.y = xq;
        v2f xs0 = dpp2<DPP_BC0>(xqd);
        v2f xs1 = dpp2<DPP_BC1>(xqd);
        v2f xs2 = dpp2<DPP_BC2>(xqd);
        v2f xs3 = dpp2<DPP_BC3>(xqd);
        za01[0] = pk_fma(W0_01, xs0, B2_01); za23[0] = pk_fma(W0_23, xs0, B2_23);
        za01[1] = pk_fma(W0_01, xs1, B2_01); za23[1] = pk_fma(W0_23, xs1, B2_23);
        za01[2] = pk_fma(W0_01, xs2, B2_01); za23[2] = pk_fma(W0_23, xs2, B2_23);
        za01[3] = pk_fma(W0_01, xs3, B2_01); za23[3] = pk_fma(W0_23, xs3, B2_23);
    };

    auto step = [&](v2f za01, v2f za23, int s, bool emit) {
        v2f h1 = dpp2<DPP_XOR1>(hd);
        v2f h2 = dpp2<DPP_XOR2>(hd);
        v2f h3 = dpp2<DPP_XOR3>(hd);
        v2f z01 = pk_fma(Wh01[0], hd, za01);
        z01 = pk_fma(Wh01[1], h1, z01);
        z01 = pk_fma(Wh01[2], h2, z01);
        z01 = pk_fma(Wh01[3], h3, z01);
        v2f z23 = pk_fma(Wh23[0], hd, za23);
        z23 = pk_fma(Wh23[1], h1, z23);
        z23 = pk_fma(Wh23[2], h2, z23);
        z23 = pk_fma(Wh23[3], h3, z23);

        v2f r01 = pk_mul(z01, itp2), r23 = pk_mul(z23, itp2);
        v2f ct01, ct23;
        ct01.x = __builtin_amdgcn_cosf(r01.x); ct01.y = __builtin_amdgcn_cosf(r01.y);
        ct23.x = __builtin_amdgcn_cosf(r23.x); ct23.y = __builtin_amdgcn_cosf(r23.y);

        // per-wire products: Z0=c1c2c3, Z1=c0c1, Z2=c0c1c2, Z3=c0c1c2c3
        v2f x1_01 = dpp2<DPP_XOR1>(ct01), x1_23 = dpp2<DPP_XOR1>(ct23);
        v2f m1_01 = pk_mul(ct01, x1_01),  m1_23 = pk_mul(ct23, x1_23);
        v2f m2_01 = dpp2<DPP_XOR2>(m1_01), m2_23 = dpp2<DPP_XOR2>(m1_23);
        v2f a01 = w_odd ? m1_01 : (w_is0 ? x1_01 : ct01);
        v2f a23 = w_odd ? m1_23 : (w_is0 ? x1_23 : ct23);
        v2f b01 = w_is1 ? one2 : m2_01;
        v2f b23 = w_is1 ? one2 : m2_23;
        v2f Z01 = pk_mul(a01, b01);   // {Zf, Zi}
        v2f Z23 = pk_mul(a23, b23);   // {Zu, Zo}

        // f,i = sigma(Z01): packed poly, no trans
        v2f y2 = pk_mul(Z01, half2), t2 = pk_mul(y2, y2);
        v2f p2 = pk_fma(t2, sp4, sp3);
        p2 = pk_fma(t2, p2, sp2);
        p2 = pk_fma(t2, p2, sp1);
        p2 = pk_fma(t2, p2, half2);
        v2f sig = pk_fma(y2, p2, half2);

        // o = sigma(Z23.y): scalar poly
        float yo = 0.5f * Z23.y, to = yo * yo;
        float po = __builtin_fmaf(to, SP4, SP3);
        po = __builtin_fmaf(to, po, SP2);
        po = __builtin_fmaf(to, po, SP1);
        po = __builtin_fmaf(to, po, 0.5f);
        float og = __builtin_fmaf(yo, po, 0.5f);

        // u = tanh(Z23.x): Pade CF4 (|x|<=1, err ~5e-6), 1 rcp
        float xu = Z23.x, tu = xu * xu;
        float nu = __builtin_fmaf(tu, 10.0f, 105.0f);
        float du = __builtin_fmaf(tu, 45.0f + tu, 105.0f);
        float ug = (xu * nu) * rcp_f(du);

        c = __builtin_fmaf(sig.x, c, sig.y * ug);

        // tanh(c): Pade CF6 (|c|<=2.1, err <1e-6), 1 rcp
        float tc = c * c;
        float nc = __builtin_fmaf(tc, 21.0f, 1260.0f);
        nc = __builtin_fmaf(tc, nc, 10395.0f);
        float dc = 210.0f + tc;
        dc = __builtin_fmaf(tc, dc, 4725.0f);
        dc = __builtin_fmaf(tc, dc, 10395.0f);
        h = og * ((c * nc) * rcp_f(dc));
        hd.x = h; hd.y = h;

        if (emit) {
            float p = h * wo_w;
            p += dppx<DPP_XOR1>(p);
            p += dppx<DPP_XOR2>(p);
            ysave = (w == s) ? (p + bout0) : ysave;
        }
    };

    auto run4 = [&](v2f* za01, v2f* za23, int t0) {
        bool emit = (t0 >= c0);                       // wave-uniform
        step(za01[0], za23[0], 0, emit);
        step(za01[1], za23[1], 1, emit);
        step(za01[2], za23[2], 2, emit);
        step(za01[3], za23[3], 3, emit);
        if (emit)
            out[(size_t)(t0 + w) * BATCH + elem] = ysave;  // 1 store / 4 steps
    };

    // software pipeline: za one block ahead; block count (tend-s0)/4 is even
    v2f zaA01[4], zaA23[4], zaB01[4], zaB23[4];
    float4 vxB = ldx(s0 + 4);
    {
        float4 vxA = ldx(s0);
        make_za(vxA, zaA01, zaA23);
    }
    for (int t0 = s0; t0 < tend; t0 += 8) {
        float4 vxN = ldx(t0 + 8);                     // prefetch 2 blocks ahead
        make_za(vxB, zaB01, zaB23);                   // za for phase B (off-chain)
        run4(zaA01, zaA23, t0);
        float4 vxN2 = ldx(t0 + 12);
        make_za(vxN, zaA01, zaA23);                   // za for next phase A
        run4(zaB01, zaB23, t0 + 4);
        vxB = vxN2;
    }
}

// ---------------- Host: LUT for the fixed random circuit ----------------
static void compute_lut(float out[16]) {
    static const double u[8] = {
        0.5488135039273248, 0.7151893663724195, 0.6027633760716439, 0.5448831829968969,
        0.4236547993389047, 0.6458941130666561, 0.4375872112626925, 0.8917730007820798
    };
    double ang[8];
    for (int k = 0; k < 8; ++k)
        ang[k] = (double)(float)(u[k] * 2.0 * 3.14159265358979323846);

    for (int p = 0; p < 16; ++p) {
        double a[16] = {0.0};
        a[p] = 1.0;
        for (int layer = 0; layer < 2; ++layer) {
            for (int w = 0; w < 4; ++w) {
                double th = ang[layer * 4 + w] * 0.5;
                double cth = cos(th), sth = sin(th);
                int bit = 1 << (3 - w);
                for (int i = 0; i < 16; ++i) if (!(i & bit)) {
                    double a0 = a[i], a1 = a[i | bit];
                    a[i]       = cth * a0 - sth * a1;
                    a[i | bit] = sth * a0 + cth * a1;
                }
            }
            for (int w = 0; w < 3; ++w) {
                int cb = 1 << (3 - w), tb = 1 << (3 - (w + 1));
                for (int i = 0; i < 16; ++i) if ((i & cb) && !(i & tb)) {
                    double tmp = a[i]; a[i] = a[i | tb]; a[i | tb] = tmp;
                }
            }
        }
        double s = 0.0;
        for (int w = 0; w < 4; ++w) {
            int bit = 1 << (3 - w);
            for (int i = 0; i < 16; ++i) if (i & bit) s += a[i] * a[i];
        }
        out[p] = (float)(s * 0.25);
    }
}

extern "C" void kernel_launch(void* const* d_in, const int* in_sizes, int n_in,
                              void* d_out, int out_size, void* d_ws, size_t ws_size,
                              hipStream_t stream) {
    const float* x = (const float*)d_in[0];
    const float *Wf, *bf, *rxf, *Wi, *bi, *rxi, *Wu, *bu, *rxu, *Wo, *bo, *rxo, *Wout, *bout;
    if (in_sizes[3] == 20) {
        Wf  = (const float*)d_in[1];  bf  = (const float*)d_in[2];
        Wi  = (const float*)d_in[3];  bi  = (const float*)d_in[4];
        Wu  = (const float*)d_in[5];  bu  = (const float*)d_in[6];
        Wo  = (const float*)d_in[7];  bo  = (const float*)d_in[8];
        rxf = (const float*)d_in[9];  rxi = (const float*)d_in[10];
        rxu = (const float*)d_in[11]; rxo = (const float*)d_in[12];
    } else {
        Wf  = (const float*)d_in[1];  bf  = (const float*)d_in[2];  rxf = (const float*)d_in[3];
        Wi  = (const float*)d_in[4];  bi  = (const float*)d_in[5];  rxi = (const float*)d_in[6];
        Wu  = (const float*)d_in[7];  bu  = (const float*)d_in[8];  rxu = (const float*)d_in[9];
        Wo  = (const float*)d_in[10]; bo  = (const float*)d_in[11]; rxo = (const float*)d_in[12];
    }
    Wout = (const float*)d_in[13];
    bout = (const float*)d_in[14];

    Lut16 lut;
    compute_lut(lut.v);

    const int lstm_threads = BATCH * CHUNKS * 4;   // 131072
    lstm_fused_kernel<<<lstm_threads / 256, 256, 0, stream>>>(x,
        Wf, bf, rxf, Wi, bi, rxi, Wu, bu, rxu, Wo, bo, rxo,
        Wout, bout, lut, (float*)d_out);
}